// Round 1
// baseline (981.271 us; speedup 1.0000x reference)
//
#include <hip/hip_runtime.h>
#include <hip/hip_bf16.h>
#include <math.h>

#define BATCH 4096
#define XD    784
#define HDIM  512
#define ZD    16
#define NS    8
#define ZS    128
#define NSAMP (BATCH * NS)   // 32768
#define STDN  (ZD * NS * NS) // 1024

// ---------------------------------------------------------------------------
// C[M,N] = act(A[M,K] @ W[K,N] + bias[N])   ACT: 0=none, 1=relu
// 64x64 tile, 256 threads, 4x4 micro-tile, A staged k-major (transposed) in LDS.
// Requires M%64==0, N%64==0, K%16==0.
// ---------------------------------------------------------------------------
template<int ACT>
__global__ __launch_bounds__(256)
void gemm_bias(const float* __restrict__ A, const float* __restrict__ W,
               const float* __restrict__ bias, float* __restrict__ C,
               int M, int N, int K)
{
    __shared__ float As[16][68];   // [kk][m]  (transposed A tile, pad 64->68)
    __shared__ float Ws[16][68];   // [kk][n]  (pad 64->68)

    const int tid = threadIdx.x;
    const int bm = blockIdx.x * 64;
    const int bn = blockIdx.y * 64;
    const int tr = tid >> 4;            // 0..15 : rows tr*4..tr*4+3
    const int tc = tid & 15;            // 0..15 : cols tc*4..tc*4+3
    const int la_m = tid >> 2;          // 0..63
    const int la_k = (tid & 3) * 4;     // 0,4,8,12
    const int lw_k = tid >> 4;          // 0..15
    const int lw_n = (tid & 15) * 4;    // 0..60

    float acc[4][4];
    #pragma unroll
    for (int i = 0; i < 4; ++i)
        #pragma unroll
        for (int j = 0; j < 4; ++j) acc[i][j] = 0.f;

    for (int k0 = 0; k0 < K; k0 += 16) {
        float4 av = *reinterpret_cast<const float4*>(&A[(size_t)(bm + la_m) * K + k0 + la_k]);
        float4 wv = *reinterpret_cast<const float4*>(&W[(size_t)(k0 + lw_k) * N + bn + lw_n]);
        __syncthreads();   // protect previous iteration's LDS reads
        As[la_k + 0][la_m] = av.x;
        As[la_k + 1][la_m] = av.y;
        As[la_k + 2][la_m] = av.z;
        As[la_k + 3][la_m] = av.w;
        *reinterpret_cast<float4*>(&Ws[lw_k][lw_n]) = wv;
        __syncthreads();
        #pragma unroll
        for (int kk = 0; kk < 16; ++kk) {
            float4 a = *reinterpret_cast<const float4*>(&As[kk][tr * 4]);
            float4 b = *reinterpret_cast<const float4*>(&Ws[kk][tc * 4]);
            acc[0][0] += a.x * b.x; acc[0][1] += a.x * b.y; acc[0][2] += a.x * b.z; acc[0][3] += a.x * b.w;
            acc[1][0] += a.y * b.x; acc[1][1] += a.y * b.y; acc[1][2] += a.y * b.z; acc[1][3] += a.y * b.w;
            acc[2][0] += a.z * b.x; acc[2][1] += a.z * b.y; acc[2][2] += a.z * b.z; acc[2][3] += a.z * b.w;
            acc[3][0] += a.w * b.x; acc[3][1] += a.w * b.y; acc[3][2] += a.w * b.z; acc[3][3] += a.w * b.w;
        }
    }

    const float b0 = bias[bn + tc * 4 + 0];
    const float b1v = bias[bn + tc * 4 + 1];
    const float b2 = bias[bn + tc * 4 + 2];
    const float b3 = bias[bn + tc * 4 + 3];
    #pragma unroll
    for (int i = 0; i < 4; ++i) {
        float4 v;
        v.x = acc[i][0] + b0;
        v.y = acc[i][1] + b1v;
        v.z = acc[i][2] + b2;
        v.w = acc[i][3] + b3;
        if (ACT == 1) {
            v.x = fmaxf(v.x, 0.f); v.y = fmaxf(v.y, 0.f);
            v.z = fmaxf(v.z, 0.f); v.w = fmaxf(v.w, 0.f);
        }
        *reinterpret_cast<float4*>(&C[(size_t)(bm + tr * 4 + i) * N + bn + tc * 4]) = v;
    }
}

// ---------------------------------------------------------------------------
// Sparse sample: z = mu + A@eps, logvar = log(diag(A A^T))
// A row r (=s1*16+d) has nonzeros vals[b,r,k]=std1[b, r*8+k] at cols d+16k.
// z/logvar reshape: (b, r) -> row b*8 + (r>>4), col r&15.
// ---------------------------------------------------------------------------
__global__ __launch_bounds__(256)
void sample_kernel(const float* __restrict__ std1, const float* __restrict__ mu,
                   const float* __restrict__ eps,
                   float* __restrict__ z_out, float* __restrict__ logvar_out)
{
    const int idx = blockIdx.x * 256 + threadIdx.x;   // 0 .. B*ZS-1
    const int b = idx >> 7;
    const int r = idx & 127;
    const int d = r & 15;
    const int s1 = r >> 4;

    const float* v = &std1[(size_t)b * STDN + r * NS];
    const float* e = &eps[(size_t)b * ZS + d];
    float zacc = 0.f, dacc = 0.f;
    #pragma unroll
    for (int k = 0; k < NS; ++k) {
        const float vv = v[k];
        zacc += vv * e[16 * k];
        dacc += vv * vv;
    }
    const float zv = mu[(size_t)b * ZS + r] + zacc;
    const size_t orow = (size_t)(b * NS + s1) * ZD + d;
    z_out[orow] = zv;
    logvar_out[orow] = logf(dacc);
}

// ---------------------------------------------------------------------------
// Fused decoder: hd = relu(z@Wd1 + bd1) staged in LDS (32x512 = 64 KiB),
// recon = sigmoid(hd @ Wd2 + bd2). Block = 32 z-rows x all 784 cols.
// ---------------------------------------------------------------------------
__global__ __launch_bounds__(256)
void decoder_kernel(const float* __restrict__ z,
                    const float* __restrict__ Wd1, const float* __restrict__ bd1,
                    const float* __restrict__ Wd2, const float* __restrict__ bd2,
                    float* __restrict__ recon)
{
    __shared__ float hd[32][512];   // exactly 64 KiB
    const int tid = threadIdx.x;
    const int row0 = blockIdx.x * 32;

    // stage 1: hd = relu(z @ Wd1 + bd1); z rows read from global (L1/L2-hot)
    for (int o = tid; o < 32 * 512; o += 256) {
        const int r = o >> 9;
        const int n = o & 511;
        const float* zr = &z[(size_t)(row0 + r) * ZD];
        float a = bd1[n];
        #pragma unroll
        for (int k = 0; k < ZD; ++k) a += zr[k] * Wd1[k * HDIM + n];
        hd[r][n] = fmaxf(a, 0.f);
    }
    __syncthreads();

    // stage 2: 32x784 output tile; threads = 8 row-groups x 32 col-groups
    const int trr = tid >> 5;   // 0..7  -> rows trr*4 .. trr*4+3
    const int tcg = tid & 31;   // 0..31 -> cols (c0 + tcg*4) .. +3
    for (int c0 = 0; c0 < XD; c0 += 128) {
        const int c = c0 + tcg * 4;
        if (c + 3 < XD) {                 // 784 = 6*128 + 16: tail has tcg<4
            float acc[4][4];
            #pragma unroll
            for (int i = 0; i < 4; ++i)
                #pragma unroll
                for (int j = 0; j < 4; ++j) acc[i][j] = 0.f;

            for (int k4 = 0; k4 < HDIM; k4 += 4) {
                float4 a[4], w[4];
                #pragma unroll
                for (int i = 0; i < 4; ++i)
                    a[i] = *reinterpret_cast<const float4*>(&hd[trr * 4 + i][k4]);
                #pragma unroll
                for (int q = 0; q < 4; ++q)
                    w[q] = *reinterpret_cast<const float4*>(&Wd2[(size_t)(k4 + q) * XD + c]);
                #pragma unroll
                for (int i = 0; i < 4; ++i) {
                    acc[i][0] += a[i].x * w[0].x + a[i].y * w[1].x + a[i].z * w[2].x + a[i].w * w[3].x;
                    acc[i][1] += a[i].x * w[0].y + a[i].y * w[1].y + a[i].z * w[2].y + a[i].w * w[3].y;
                    acc[i][2] += a[i].x * w[0].z + a[i].y * w[1].z + a[i].z * w[2].z + a[i].w * w[3].z;
                    acc[i][3] += a[i].x * w[0].w + a[i].y * w[1].w + a[i].z * w[2].w + a[i].w * w[3].w;
                }
            }
            const float bb0 = bd2[c + 0], bb1 = bd2[c + 1], bb2 = bd2[c + 2], bb3 = bd2[c + 3];
            #pragma unroll
            for (int i = 0; i < 4; ++i) {
                float4 v;
                v.x = 1.f / (1.f + __expf(-(acc[i][0] + bb0)));
                v.y = 1.f / (1.f + __expf(-(acc[i][1] + bb1)));
                v.z = 1.f / (1.f + __expf(-(acc[i][2] + bb2)));
                v.w = 1.f / (1.f + __expf(-(acc[i][3] + bb3)));
                *reinterpret_cast<float4*>(&recon[(size_t)(row0 + trr * 4 + i) * XD + c]) = v;
            }
        }
    }
}

// ---------------------------------------------------------------------------
extern "C" void kernel_launch(void* const* d_in, const int* in_sizes, int n_in,
                              void* d_out, int out_size, void* d_ws, size_t ws_size,
                              hipStream_t stream)
{
    const float* x    = (const float*)d_in[0];
    const float* eps  = (const float*)d_in[1];
    const float* W1   = (const float*)d_in[2];
    const float* b1   = (const float*)d_in[3];
    const float* Wmu  = (const float*)d_in[4];
    const float* bmu  = (const float*)d_in[5];
    const float* Wstd = (const float*)d_in[6];
    const float* bstd = (const float*)d_in[7];
    const float* Wd1  = (const float*)d_in[8];
    const float* bd1  = (const float*)d_in[9];
    const float* Wd2  = (const float*)d_in[10];
    const float* bd2  = (const float*)d_in[11];

    float* out    = (float*)d_out;
    float* recon  = out;                                  // 32768*784
    float* mu     = recon + (size_t)NSAMP * XD;           // 4096*128
    float* logvar = mu + (size_t)BATCH * ZS;              // 32768*16
    float* zout   = logvar + (size_t)NSAMP * ZD;          // 32768*16

    float* ws   = (float*)d_ws;
    float* h    = ws;                                     // 4096*512  f32
    float* std1 = h + (size_t)BATCH * HDIM;               // 4096*1024 f32

    // encode
    gemm_bias<1><<<dim3(BATCH / 64, HDIM / 64), 256, 0, stream>>>(x, W1, b1, h, BATCH, HDIM, XD);
    gemm_bias<0><<<dim3(BATCH / 64, ZS / 64), 256, 0, stream>>>(h, Wmu, bmu, mu, BATCH, ZS, HDIM);
    gemm_bias<0><<<dim3(BATCH / 64, STDN / 64), 256, 0, stream>>>(h, Wstd, bstd, std1, BATCH, STDN, HDIM);
    // sample + logvar (z written to its output slot; decoder reads it back)
    sample_kernel<<<(BATCH * ZS) / 256, 256, 0, stream>>>(std1, mu, eps, zout, logvar);
    // decode
    decoder_kernel<<<NSAMP / 32, 256, 0, stream>>>(zout, Wd1, bd1, Wd2, bd2, recon);
}

// Round 2
// 252.613 us; speedup vs baseline: 3.8845x; 3.8845x over previous
//
#include <hip/hip_runtime.h>
#include <hip/hip_bf16.h>
#include <math.h>

#define BATCH 4096
#define XD    784
#define HDIM  512
#define ZD    16
#define NS    8
#define ZS    128
#define NSAMP (BATCH * NS)   // 32768
#define STDN  (ZD * NS * NS) // 1024

typedef __attribute__((ext_vector_type(8))) short bf16x8;
typedef __attribute__((ext_vector_type(4))) float f32x4;

__device__ inline unsigned short f2bf(float f) {
    unsigned int u = __float_as_uint(f);
    unsigned int r = (u + 0x7fffu + ((u >> 16) & 1u)) >> 16;
    return (unsigned short)r;
}

// ---------------------------------------------------------------------------
// f32 GEMM with bias (+optional relu) — encoder path (unchanged from R0).
// ---------------------------------------------------------------------------
template<int ACT>
__global__ __launch_bounds__(256)
void gemm_bias(const float* __restrict__ A, const float* __restrict__ W,
               const float* __restrict__ bias, float* __restrict__ C,
               int M, int N, int K)
{
    __shared__ float As[16][68];
    __shared__ float Ws[16][68];

    const int tid = threadIdx.x;
    const int bm = blockIdx.x * 64;
    const int bn = blockIdx.y * 64;
    const int tr = tid >> 4;
    const int tc = tid & 15;
    const int la_m = tid >> 2;
    const int la_k = (tid & 3) * 4;
    const int lw_k = tid >> 4;
    const int lw_n = (tid & 15) * 4;

    float acc[4][4];
    #pragma unroll
    for (int i = 0; i < 4; ++i)
        #pragma unroll
        for (int j = 0; j < 4; ++j) acc[i][j] = 0.f;

    for (int k0 = 0; k0 < K; k0 += 16) {
        float4 av = *reinterpret_cast<const float4*>(&A[(size_t)(bm + la_m) * K + k0 + la_k]);
        float4 wv = *reinterpret_cast<const float4*>(&W[(size_t)(k0 + lw_k) * N + bn + lw_n]);
        __syncthreads();
        As[la_k + 0][la_m] = av.x;
        As[la_k + 1][la_m] = av.y;
        As[la_k + 2][la_m] = av.z;
        As[la_k + 3][la_m] = av.w;
        *reinterpret_cast<float4*>(&Ws[lw_k][lw_n]) = wv;
        __syncthreads();
        #pragma unroll
        for (int kk = 0; kk < 16; ++kk) {
            float4 a = *reinterpret_cast<const float4*>(&As[kk][tr * 4]);
            float4 b = *reinterpret_cast<const float4*>(&Ws[kk][tc * 4]);
            acc[0][0] += a.x * b.x; acc[0][1] += a.x * b.y; acc[0][2] += a.x * b.z; acc[0][3] += a.x * b.w;
            acc[1][0] += a.y * b.x; acc[1][1] += a.y * b.y; acc[1][2] += a.y * b.z; acc[1][3] += a.y * b.w;
            acc[2][0] += a.z * b.x; acc[2][1] += a.z * b.y; acc[2][2] += a.z * b.z; acc[2][3] += a.z * b.w;
            acc[3][0] += a.w * b.x; acc[3][1] += a.w * b.y; acc[3][2] += a.w * b.z; acc[3][3] += a.w * b.w;
        }
    }

    const float b0 = bias[bn + tc * 4 + 0];
    const float b1v = bias[bn + tc * 4 + 1];
    const float b2 = bias[bn + tc * 4 + 2];
    const float b3 = bias[bn + tc * 4 + 3];
    #pragma unroll
    for (int i = 0; i < 4; ++i) {
        float4 v;
        v.x = acc[i][0] + b0;
        v.y = acc[i][1] + b1v;
        v.z = acc[i][2] + b2;
        v.w = acc[i][3] + b3;
        if (ACT == 1) {
            v.x = fmaxf(v.x, 0.f); v.y = fmaxf(v.y, 0.f);
            v.z = fmaxf(v.z, 0.f); v.w = fmaxf(v.w, 0.f);
        }
        *reinterpret_cast<float4*>(&C[(size_t)(bm + tr * 4 + i) * N + bn + tc * 4]) = v;
    }
}

// ---------------------------------------------------------------------------
// Sparse sample: z = mu + A@eps, logvar = log(diag(A A^T))  (unchanged)
// ---------------------------------------------------------------------------
__global__ __launch_bounds__(256)
void sample_kernel(const float* __restrict__ std1, const float* __restrict__ mu,
                   const float* __restrict__ eps,
                   float* __restrict__ z_out, float* __restrict__ logvar_out)
{
    const int idx = blockIdx.x * 256 + threadIdx.x;
    const int b = idx >> 7;
    const int r = idx & 127;
    const int d = r & 15;
    const int s1 = r >> 4;

    const float* v = &std1[(size_t)b * STDN + r * NS];
    const float* e = &eps[(size_t)b * ZS + d];
    float zacc = 0.f, dacc = 0.f;
    #pragma unroll
    for (int k = 0; k < NS; ++k) {
        const float vv = v[k];
        zacc += vv * e[16 * k];
        dacc += vv * vv;
    }
    const float zv = mu[(size_t)b * ZS + r] + zacc;
    const size_t orow = (size_t)(b * NS + s1) * ZD + d;
    z_out[orow] = zv;
    logvar_out[orow] = logf(dacc);
}

// ---------------------------------------------------------------------------
// Wd2 [512][784] f32  ->  w2t [784][512] bf16 (transposed, k contiguous)
// ---------------------------------------------------------------------------
__global__ __launch_bounds__(256)
void wd2t_kernel(const float* __restrict__ Wd2, unsigned short* __restrict__ w2t)
{
    __shared__ unsigned short t[16][17];
    const int tx = threadIdx.x & 15;
    const int ty = threadIdx.x >> 4;
    const int n = blockIdx.x * 16 + tx;
    const int k = blockIdx.y * 16 + ty;
    t[ty][tx] = f2bf(Wd2[(size_t)k * XD + n]);
    __syncthreads();
    const int on = blockIdx.x * 16 + ty;
    const int ok = blockIdx.y * 16 + tx;
    w2t[(size_t)on * HDIM + ok] = t[tx][ty];
}

// ---------------------------------------------------------------------------
// hd = relu(z @ Wd1 + bd1) in bf16.  M=32768, K=16, N=512.
// ---------------------------------------------------------------------------
__global__ __launch_bounds__(256)
void hd_kernel(const float* __restrict__ z, const float* __restrict__ Wd1,
               const float* __restrict__ bd1, unsigned short* __restrict__ hd)
{
    const int idx = blockIdx.x * 256 + threadIdx.x;   // 0 .. 32768*128-1
    const int m = idx >> 7;
    const int n0 = (idx & 127) * 4;
    const float* zr = &z[(size_t)m * ZD];
    float4 a = *reinterpret_cast<const float4*>(&bd1[n0]);
    #pragma unroll
    for (int k = 0; k < ZD; ++k) {
        const float zk = zr[k];
        float4 w = *reinterpret_cast<const float4*>(&Wd1[(size_t)k * HDIM + n0]);
        a.x += zk * w.x; a.y += zk * w.y; a.z += zk * w.z; a.w += zk * w.w;
    }
    ushort4 o;
    o.x = f2bf(fmaxf(a.x, 0.f));
    o.y = f2bf(fmaxf(a.y, 0.f));
    o.z = f2bf(fmaxf(a.z, 0.f));
    o.w = f2bf(fmaxf(a.w, 0.f));
    *reinterpret_cast<ushort4*>(&hd[(size_t)m * HDIM + n0]) = o;
}

// ---------------------------------------------------------------------------
// Decoder GEMM via MFMA: recon = sigmoid(hd @ Wd2 + bd2)
// M=32768, N=784, K=512. BM=128, BN=112, BK=32. 4 waves, double-buffered LDS.
// Fragment layout (mfma_f32_16x16x32_bf16, m89-verified):
//   A: row=lane&15, k=(lane>>4)*8+j   B: col=lane&15, k=(lane>>4)*8+j
//   D: col=lane&15, row=(lane>>4)*4+reg
// ---------------------------------------------------------------------------
#define DBM 128
#define DBN 112
#define DNKT 16      // K/32
#define LPAD 40      // LDS row stride in bf16 (pad 32->40: 2-way bank alias = free)

__global__ __launch_bounds__(256)
void decoder_mfma(const unsigned short* __restrict__ hd,
                  const unsigned short* __restrict__ w2t,
                  const float* __restrict__ bd2,
                  float* __restrict__ recon)
{
    __shared__ __align__(16) unsigned short Al[2][DBM][LPAD];
    __shared__ __align__(16) unsigned short Bl[2][DBN][LPAD];

    const int tid = threadIdx.x;
    const int m0 = blockIdx.x * DBM;
    const int n0 = blockIdx.y * DBN;
    const int wave = tid >> 6;
    const int lane = tid & 63;
    const int lr = lane & 15;
    const int kg = lane >> 4;

    f32x4 acc[2][7];
    #pragma unroll
    for (int i = 0; i < 2; ++i)
        #pragma unroll
        for (int j = 0; j < 7; ++j)
            acc[i][j] = (f32x4){0.f, 0.f, 0.f, 0.f};

    // prologue: stage kt=0 into buffer 0
    {
        for (int u = tid; u < 512; u += 256) {
            const int r = u >> 2, ks = u & 3;
            *reinterpret_cast<int4*>(&Al[0][r][ks * 8]) =
                *reinterpret_cast<const int4*>(&hd[(size_t)(m0 + r) * HDIM + ks * 8]);
        }
        for (int u = tid; u < 448; u += 256) {
            const int r = u >> 2, ks = u & 3;
            *reinterpret_cast<int4*>(&Bl[0][r][ks * 8]) =
                *reinterpret_cast<const int4*>(&w2t[(size_t)(n0 + r) * HDIM + ks * 8]);
        }
    }
    __syncthreads();

    int buf = 0;
    for (int kt = 0; kt < DNKT; ++kt) {
        int4 sa0, sa1, sb0, sb1;
        const bool pf = (kt + 1 < DNKT);
        if (pf) {
            const int k0 = (kt + 1) * 32;
            { const int u = tid;       sa0 = *reinterpret_cast<const int4*>(&hd[(size_t)(m0 + (u >> 2)) * HDIM + k0 + (u & 3) * 8]); }
            { const int u = tid + 256; sa1 = *reinterpret_cast<const int4*>(&hd[(size_t)(m0 + (u >> 2)) * HDIM + k0 + (u & 3) * 8]); }
            { const int u = tid;       sb0 = *reinterpret_cast<const int4*>(&w2t[(size_t)(n0 + (u >> 2)) * HDIM + k0 + (u & 3) * 8]); }
            if (tid < 192) { const int u = tid + 256; sb1 = *reinterpret_cast<const int4*>(&w2t[(size_t)(n0 + (u >> 2)) * HDIM + k0 + (u & 3) * 8]); }
        }

        bf16x8 af[2], bfr[7];
        #pragma unroll
        for (int mi = 0; mi < 2; ++mi)
            af[mi] = *reinterpret_cast<const bf16x8*>(&Al[buf][wave * 32 + mi * 16 + lr][kg * 8]);
        #pragma unroll
        for (int nf = 0; nf < 7; ++nf)
            bfr[nf] = *reinterpret_cast<const bf16x8*>(&Bl[buf][nf * 16 + lr][kg * 8]);
        #pragma unroll
        for (int mi = 0; mi < 2; ++mi)
            #pragma unroll
            for (int nf = 0; nf < 7; ++nf)
                acc[mi][nf] = __builtin_amdgcn_mfma_f32_16x16x32_bf16(af[mi], bfr[nf], acc[mi][nf], 0, 0, 0);

        if (pf) {
            const int nb = buf ^ 1;
            { const int u = tid;       *reinterpret_cast<int4*>(&Al[nb][u >> 2][(u & 3) * 8]) = sa0; }
            { const int u = tid + 256; *reinterpret_cast<int4*>(&Al[nb][u >> 2][(u & 3) * 8]) = sa1; }
            { const int u = tid;       *reinterpret_cast<int4*>(&Bl[nb][u >> 2][(u & 3) * 8]) = sb0; }
            if (tid < 192) { const int u = tid + 256; *reinterpret_cast<int4*>(&Bl[nb][u >> 2][(u & 3) * 8]) = sb1; }
        }
        __syncthreads();
        buf ^= 1;
    }

    // epilogue: bias + sigmoid, f32 store
    const int mrow = m0 + wave * 32;
    #pragma unroll
    for (int nf = 0; nf < 7; ++nf) {
        const int col = n0 + nf * 16 + lr;
        const float bias = bd2[col];
        #pragma unroll
        for (int mi = 0; mi < 2; ++mi) {
            #pragma unroll
            for (int j = 0; j < 4; ++j) {
                const int row = mrow + mi * 16 + kg * 4 + j;
                const float v = acc[mi][nf][j] + bias;
                recon[(size_t)row * XD + col] = 1.f / (1.f + __expf(-v));
            }
        }
    }
}

// ---------------------------------------------------------------------------
extern "C" void kernel_launch(void* const* d_in, const int* in_sizes, int n_in,
                              void* d_out, int out_size, void* d_ws, size_t ws_size,
                              hipStream_t stream)
{
    const float* x    = (const float*)d_in[0];
    const float* eps  = (const float*)d_in[1];
    const float* W1   = (const float*)d_in[2];
    const float* b1   = (const float*)d_in[3];
    const float* Wmu  = (const float*)d_in[4];
    const float* bmu  = (const float*)d_in[5];
    const float* Wstd = (const float*)d_in[6];
    const float* bstd = (const float*)d_in[7];
    const float* Wd1  = (const float*)d_in[8];
    const float* bd1  = (const float*)d_in[9];
    const float* Wd2  = (const float*)d_in[10];
    const float* bd2  = (const float*)d_in[11];

    float* out    = (float*)d_out;
    float* recon  = out;                                  // 32768*784
    float* mu     = recon + (size_t)NSAMP * XD;           // 4096*128
    float* logvar = mu + (size_t)BATCH * ZS;              // 32768*16
    float* zout   = logvar + (size_t)NSAMP * ZD;          // 32768*16

    // ws layout (time-multiplexed):
    //   [0, 32M)      : hd bf16 (written AFTER h/std1 are dead)
    //   [0, 8M)       : h f32        (live: k_h .. k_std1)
    //   [8M, 24M)     : std1 f32     (live: k_std1 .. sample)
    //   [32M, 32.8M)  : w2t bf16     (live: start .. decoder)
    char* wsb = (char*)d_ws;
    unsigned short* hd  = (unsigned short*)wsb;
    float* h    = (float*)wsb;
    float* std1 = (float*)(wsb + (size_t)8 * 1024 * 1024);
    unsigned short* w2t = (unsigned short*)(wsb + (size_t)32 * 1024 * 1024);

    // Wd2 transpose+bf16 (independent — launch first)
    wd2t_kernel<<<dim3(XD / 16, HDIM / 16), 256, 0, stream>>>(Wd2, w2t);

    // encode (f32)
    gemm_bias<1><<<dim3(BATCH / 64, HDIM / 64), 256, 0, stream>>>(x, W1, b1, h, BATCH, HDIM, XD);
    gemm_bias<0><<<dim3(BATCH / 64, ZS / 64), 256, 0, stream>>>(h, Wmu, bmu, mu, BATCH, ZS, HDIM);
    gemm_bias<0><<<dim3(BATCH / 64, STDN / 64), 256, 0, stream>>>(h, Wstd, bstd, std1, BATCH, STDN, HDIM);

    // sample + logvar
    sample_kernel<<<(BATCH * ZS) / 256, 256, 0, stream>>>(std1, mu, eps, zout, logvar);

    // decoder hidden layer -> bf16 (overwrites dead h/std1 regions)
    hd_kernel<<<(NSAMP * 128) / 256, 256, 0, stream>>>(zout, Wd1, bd1, hd);

    // decoder GEMM on matrix cores
    decoder_mfma<<<dim3(NSAMP / DBM, XD / DBN), 256, 0, stream>>>(hd, w2t, bd2, recon);
}

// Round 3
// 154.824 us; speedup vs baseline: 6.3380x; 1.6316x over previous
//
#include <hip/hip_runtime.h>
#include <hip/hip_bf16.h>
#include <math.h>

#define BATCH 4096
#define XD    784
#define HDIM  512
#define ZD    16
#define NS    8
#define ZS    128
#define NSAMP (BATCH * NS)   // 32768
#define STDN  (ZD * NS * NS) // 1024
#define KP1   800            // K of enc1, padded 784->800 (multiple of 32)
#define NMS   1152           // 128 (mu) + 1024 (std1)

typedef __attribute__((ext_vector_type(8))) short bf16x8;
typedef __attribute__((ext_vector_type(4))) float f32x4;

__device__ inline unsigned short f2bf(float f) {
    unsigned int u = __float_as_uint(f);
    unsigned int r = (u + 0x7fffu + ((u >> 16) & 1u)) >> 16;
    return (unsigned short)r;
}

// ---------------------------------------------------------------------------
// Generic f32->bf16 transpose with K zero-pad: Bt[n][k] (ld=KP) = W[k][n] (ld=N)
// grid (N/16, KP/16), block 256.
// ---------------------------------------------------------------------------
__global__ __launch_bounds__(256)
void transpose_bf16(const float* __restrict__ W, unsigned short* __restrict__ Bt,
                    int K, int N, int KP)
{
    __shared__ unsigned short t[16][17];
    const int tx = threadIdx.x & 15;
    const int ty = threadIdx.x >> 4;
    const int n = blockIdx.x * 16 + tx;
    const int k = blockIdx.y * 16 + ty;
    t[ty][tx] = (k < K) ? f2bf(W[(size_t)k * N + n]) : (unsigned short)0;
    __syncthreads();
    const int on = blockIdx.x * 16 + ty;
    const int ok = blockIdx.y * 16 + tx;
    Bt[(size_t)on * KP + ok] = t[tx][ty];
}

// ---------------------------------------------------------------------------
// wmst[1152][512] bf16: rows 0..127 = Wmu^T, rows 128..1151 = Wstd^T
// grid (72, 32), block 256.
// ---------------------------------------------------------------------------
__global__ __launch_bounds__(256)
void wms_t_kernel(const float* __restrict__ Wmu, const float* __restrict__ Wstd,
                  unsigned short* __restrict__ Bt)
{
    __shared__ unsigned short t[16][17];
    const int tx = threadIdx.x & 15;
    const int ty = threadIdx.x >> 4;
    const int n = blockIdx.x * 16 + tx;     // 0..1151
    const int k = blockIdx.y * 16 + ty;     // 0..511
    const float v = (n < ZS) ? Wmu[(size_t)k * ZS + n]
                             : Wstd[(size_t)k * STDN + (n - ZS)];
    t[ty][tx] = f2bf(v);
    __syncthreads();
    const int on = blockIdx.x * 16 + ty;
    const int ok = blockIdx.y * 16 + tx;
    Bt[(size_t)on * HDIM + ok] = t[tx][ty];
}

// ---------------------------------------------------------------------------
// x [4096][784] f32 -> xb [4096][800] bf16 (zero pad). 8 cols/thread.
// ---------------------------------------------------------------------------
__global__ __launch_bounds__(256)
void xpad_kernel(const float* __restrict__ x, unsigned short* __restrict__ xb)
{
    const int idx = blockIdx.x * 256 + threadIdx.x;   // 0 .. 4096*100-1
    const int row = idx / 100;
    const int c8 = idx - row * 100;
    const int k0 = c8 * 8;
    ushort4 o0 = {0, 0, 0, 0}, o1 = {0, 0, 0, 0};
    if (k0 < XD) {   // 784/8=98 full chunks; c8=98,99 are pure pad
        const float4 a = *reinterpret_cast<const float4*>(&x[(size_t)row * XD + k0]);
        const float4 b = *reinterpret_cast<const float4*>(&x[(size_t)row * XD + k0 + 4]);
        o0.x = f2bf(a.x); o0.y = f2bf(a.y); o0.z = f2bf(a.z); o0.w = f2bf(a.w);
        o1.x = f2bf(b.x); o1.y = f2bf(b.y); o1.z = f2bf(b.z); o1.w = f2bf(b.w);
    }
    *reinterpret_cast<ushort4*>(&xb[(size_t)row * KP1 + k0]) = o0;
    *reinterpret_cast<ushort4*>(&xb[(size_t)row * KP1 + k0 + 4]) = o1;
}

// ---------------------------------------------------------------------------
// Encoder MFMA GEMM: out = [relu](A @ Bt^T + bias). BM=BN=128, BK=32,
// 4 waves, double-buffered LDS. A[M][K] bf16, Bt[N][K] bf16.
// OUT_BF16=1: relu + bf16 store (ld=ldc). OUT_BF16=0: f32 store.
// bias col c: c<bsplit ? bias0[c] : bias1[c-bsplit].
// ---------------------------------------------------------------------------
#define ELPAD 40

template<int OUT_BF16>
__global__ __launch_bounds__(256)
void enc_mfma(const unsigned short* __restrict__ A,
              const unsigned short* __restrict__ Bt,
              const float* __restrict__ bias0, const float* __restrict__ bias1,
              int bsplit, void* __restrict__ Cout, int ldc, int K)
{
    __shared__ __align__(16) unsigned short Al[2][128][ELPAD];
    __shared__ __align__(16) unsigned short Bl[2][128][ELPAD];

    const int tid = threadIdx.x;
    const int m0 = blockIdx.x * 128;
    const int n0 = blockIdx.y * 128;
    const int wave = tid >> 6;
    const int lane = tid & 63;
    const int lr = lane & 15;
    const int kg = lane >> 4;
    const int nkt = K >> 5;

    f32x4 acc[2][8];
    #pragma unroll
    for (int i = 0; i < 2; ++i)
        #pragma unroll
        for (int j = 0; j < 8; ++j)
            acc[i][j] = (f32x4){0.f, 0.f, 0.f, 0.f};

    // prologue: stage kt=0
    {
        const int r = tid >> 2, ks = tid & 3;
        *reinterpret_cast<int4*>(&Al[0][r][ks * 8]) =
            *reinterpret_cast<const int4*>(&A[(size_t)(m0 + r) * K + ks * 8]);
        *reinterpret_cast<int4*>(&Al[0][r + 64][ks * 8]) =
            *reinterpret_cast<const int4*>(&A[(size_t)(m0 + r + 64) * K + ks * 8]);
        *reinterpret_cast<int4*>(&Bl[0][r][ks * 8]) =
            *reinterpret_cast<const int4*>(&Bt[(size_t)(n0 + r) * K + ks * 8]);
        *reinterpret_cast<int4*>(&Bl[0][r + 64][ks * 8]) =
            *reinterpret_cast<const int4*>(&Bt[(size_t)(n0 + r + 64) * K + ks * 8]);
    }
    __syncthreads();

    int buf = 0;
    for (int kt = 0; kt < nkt; ++kt) {
        int4 sa0, sa1, sb0, sb1;
        const bool pf = (kt + 1 < nkt);
        const int r = tid >> 2, ks = tid & 3;
        if (pf) {
            const int k0 = (kt + 1) * 32 + ks * 8;
            sa0 = *reinterpret_cast<const int4*>(&A[(size_t)(m0 + r) * K + k0]);
            sa1 = *reinterpret_cast<const int4*>(&A[(size_t)(m0 + r + 64) * K + k0]);
            sb0 = *reinterpret_cast<const int4*>(&Bt[(size_t)(n0 + r) * K + k0]);
            sb1 = *reinterpret_cast<const int4*>(&Bt[(size_t)(n0 + r + 64) * K + k0]);
        }

        bf16x8 af[2], bfr[8];
        #pragma unroll
        for (int mi = 0; mi < 2; ++mi)
            af[mi] = *reinterpret_cast<const bf16x8*>(&Al[buf][wave * 32 + mi * 16 + lr][kg * 8]);
        #pragma unroll
        for (int nf = 0; nf < 8; ++nf)
            bfr[nf] = *reinterpret_cast<const bf16x8*>(&Bl[buf][nf * 16 + lr][kg * 8]);
        #pragma unroll
        for (int mi = 0; mi < 2; ++mi)
            #pragma unroll
            for (int nf = 0; nf < 8; ++nf)
                acc[mi][nf] = __builtin_amdgcn_mfma_f32_16x16x32_bf16(af[mi], bfr[nf], acc[mi][nf], 0, 0, 0);

        if (pf) {
            const int nb = buf ^ 1;
            *reinterpret_cast<int4*>(&Al[nb][r][ks * 8]) = sa0;
            *reinterpret_cast<int4*>(&Al[nb][r + 64][ks * 8]) = sa1;
            *reinterpret_cast<int4*>(&Bl[nb][r][ks * 8]) = sb0;
            *reinterpret_cast<int4*>(&Bl[nb][r + 64][ks * 8]) = sb1;
        }
        __syncthreads();
        buf ^= 1;
    }

    const int mrow = m0 + wave * 32;
    #pragma unroll
    for (int nf = 0; nf < 8; ++nf) {
        const int col = n0 + nf * 16 + lr;
        const float bb = (col < bsplit) ? bias0[col] : bias1[col - bsplit];
        #pragma unroll
        for (int mi = 0; mi < 2; ++mi) {
            #pragma unroll
            for (int j = 0; j < 4; ++j) {
                const int row = mrow + mi * 16 + kg * 4 + j;
                const float v = acc[mi][nf][j] + bb;
                if (OUT_BF16)
                    ((unsigned short*)Cout)[(size_t)row * ldc + col] = f2bf(fmaxf(v, 0.f));
                else
                    ((float*)Cout)[(size_t)row * ldc + col] = v;
            }
        }
    }
}

// ---------------------------------------------------------------------------
// Sparse sample from combined ms=[mu|std1] (ld=1152):
// z = mu + A@eps, logvar = log(diag(A A^T)); also writes mu output.
// ---------------------------------------------------------------------------
__global__ __launch_bounds__(256)
void sample_kernel(const float* __restrict__ ms, const float* __restrict__ eps,
                   float* __restrict__ mu_out,
                   float* __restrict__ z_out, float* __restrict__ logvar_out)
{
    const int idx = blockIdx.x * 256 + threadIdx.x;   // 0 .. B*ZS-1
    const int b = idx >> 7;
    const int r = idx & 127;
    const int d = r & 15;
    const int s1 = r >> 4;

    const float* v = &ms[(size_t)b * NMS + ZS + r * NS];
    const float* e = &eps[(size_t)b * ZS + d];
    float zacc = 0.f, dacc = 0.f;
    #pragma unroll
    for (int k = 0; k < NS; ++k) {
        const float vv = v[k];
        zacc += vv * e[16 * k];
        dacc += vv * vv;
    }
    const float muv = ms[(size_t)b * NMS + r];
    mu_out[(size_t)b * ZS + r] = muv;
    const float zv = muv + zacc;
    const size_t orow = (size_t)(b * NS + s1) * ZD + d;
    z_out[orow] = zv;
    logvar_out[orow] = logf(dacc);
}

// ---------------------------------------------------------------------------
// hd = relu(z @ Wd1 + bd1) in bf16.  M=32768, K=16, N=512.
// ---------------------------------------------------------------------------
__global__ __launch_bounds__(256)
void hd_kernel(const float* __restrict__ z, const float* __restrict__ Wd1,
               const float* __restrict__ bd1, unsigned short* __restrict__ hd)
{
    const int idx = blockIdx.x * 256 + threadIdx.x;
    const int m = idx >> 7;
    const int n0 = (idx & 127) * 4;
    const float* zr = &z[(size_t)m * ZD];
    float4 a = *reinterpret_cast<const float4*>(&bd1[n0]);
    #pragma unroll
    for (int k = 0; k < ZD; ++k) {
        const float zk = zr[k];
        float4 w = *reinterpret_cast<const float4*>(&Wd1[(size_t)k * HDIM + n0]);
        a.x += zk * w.x; a.y += zk * w.y; a.z += zk * w.z; a.w += zk * w.w;
    }
    ushort4 o;
    o.x = f2bf(fmaxf(a.x, 0.f));
    o.y = f2bf(fmaxf(a.y, 0.f));
    o.z = f2bf(fmaxf(a.z, 0.f));
    o.w = f2bf(fmaxf(a.w, 0.f));
    *reinterpret_cast<ushort4*>(&hd[(size_t)m * HDIM + n0]) = o;
}

// ---------------------------------------------------------------------------
// Decoder GEMM via MFMA (unchanged from R1): recon = sigmoid(hd @ Wd2 + bd2)
// ---------------------------------------------------------------------------
#define DBM 128
#define DBN 112
#define DNKT 16
#define LPAD 40

__global__ __launch_bounds__(256)
void decoder_mfma(const unsigned short* __restrict__ hd,
                  const unsigned short* __restrict__ w2t,
                  const float* __restrict__ bd2,
                  float* __restrict__ recon)
{
    __shared__ __align__(16) unsigned short Al[2][DBM][LPAD];
    __shared__ __align__(16) unsigned short Bl[2][DBN][LPAD];

    const int tid = threadIdx.x;
    const int m0 = blockIdx.x * DBM;
    const int n0 = blockIdx.y * DBN;
    const int wave = tid >> 6;
    const int lane = tid & 63;
    const int lr = lane & 15;
    const int kg = lane >> 4;

    f32x4 acc[2][7];
    #pragma unroll
    for (int i = 0; i < 2; ++i)
        #pragma unroll
        for (int j = 0; j < 7; ++j)
            acc[i][j] = (f32x4){0.f, 0.f, 0.f, 0.f};

    {
        for (int u = tid; u < 512; u += 256) {
            const int r = u >> 2, ks = u & 3;
            *reinterpret_cast<int4*>(&Al[0][r][ks * 8]) =
                *reinterpret_cast<const int4*>(&hd[(size_t)(m0 + r) * HDIM + ks * 8]);
        }
        for (int u = tid; u < 448; u += 256) {
            const int r = u >> 2, ks = u & 3;
            *reinterpret_cast<int4*>(&Bl[0][r][ks * 8]) =
                *reinterpret_cast<const int4*>(&w2t[(size_t)(n0 + r) * HDIM + ks * 8]);
        }
    }
    __syncthreads();

    int buf = 0;
    for (int kt = 0; kt < DNKT; ++kt) {
        int4 sa0, sa1, sb0, sb1;
        const bool pf = (kt + 1 < DNKT);
        if (pf) {
            const int k0 = (kt + 1) * 32;
            { const int u = tid;       sa0 = *reinterpret_cast<const int4*>(&hd[(size_t)(m0 + (u >> 2)) * HDIM + k0 + (u & 3) * 8]); }
            { const int u = tid + 256; sa1 = *reinterpret_cast<const int4*>(&hd[(size_t)(m0 + (u >> 2)) * HDIM + k0 + (u & 3) * 8]); }
            { const int u = tid;       sb0 = *reinterpret_cast<const int4*>(&w2t[(size_t)(n0 + (u >> 2)) * HDIM + k0 + (u & 3) * 8]); }
            if (tid < 192) { const int u = tid + 256; sb1 = *reinterpret_cast<const int4*>(&w2t[(size_t)(n0 + (u >> 2)) * HDIM + k0 + (u & 3) * 8]); }
        }

        bf16x8 af[2], bfr[7];
        #pragma unroll
        for (int mi = 0; mi < 2; ++mi)
            af[mi] = *reinterpret_cast<const bf16x8*>(&Al[buf][wave * 32 + mi * 16 + lr][kg * 8]);
        #pragma unroll
        for (int nf = 0; nf < 7; ++nf)
            bfr[nf] = *reinterpret_cast<const bf16x8*>(&Bl[buf][nf * 16 + lr][kg * 8]);
        #pragma unroll
        for (int mi = 0; mi < 2; ++mi)
            #pragma unroll
            for (int nf = 0; nf < 7; ++nf)
                acc[mi][nf] = __builtin_amdgcn_mfma_f32_16x16x32_bf16(af[mi], bfr[nf], acc[mi][nf], 0, 0, 0);

        if (pf) {
            const int nb = buf ^ 1;
            { const int u = tid;       *reinterpret_cast<int4*>(&Al[nb][u >> 2][(u & 3) * 8]) = sa0; }
            { const int u = tid + 256; *reinterpret_cast<int4*>(&Al[nb][u >> 2][(u & 3) * 8]) = sa1; }
            { const int u = tid;       *reinterpret_cast<int4*>(&Bl[nb][u >> 2][(u & 3) * 8]) = sb0; }
            if (tid < 192) { const int u = tid + 256; *reinterpret_cast<int4*>(&Bl[nb][u >> 2][(u & 3) * 8]) = sb1; }
        }
        __syncthreads();
        buf ^= 1;
    }

    const int mrow = m0 + wave * 32;
    #pragma unroll
    for (int nf = 0; nf < 7; ++nf) {
        const int col = n0 + nf * 16 + lr;
        const float bias = bd2[col];
        #pragma unroll
        for (int mi = 0; mi < 2; ++mi) {
            #pragma unroll
            for (int j = 0; j < 4; ++j) {
                const int row = mrow + mi * 16 + kg * 4 + j;
                const float v = acc[mi][nf][j] + bias;
                recon[(size_t)row * XD + col] = 1.f / (1.f + __expf(-v));
            }
        }
    }
}

// ---------------------------------------------------------------------------
extern "C" void kernel_launch(void* const* d_in, const int* in_sizes, int n_in,
                              void* d_out, int out_size, void* d_ws, size_t ws_size,
                              hipStream_t stream)
{
    const float* x    = (const float*)d_in[0];
    const float* eps  = (const float*)d_in[1];
    const float* W1   = (const float*)d_in[2];
    const float* b1   = (const float*)d_in[3];
    const float* Wmu  = (const float*)d_in[4];
    const float* bmu  = (const float*)d_in[5];
    const float* Wstd = (const float*)d_in[6];
    const float* bstd = (const float*)d_in[7];
    const float* Wd1  = (const float*)d_in[8];
    const float* bd1  = (const float*)d_in[9];
    const float* Wd2  = (const float*)d_in[10];
    const float* bd2  = (const float*)d_in[11];

    float* out    = (float*)d_out;
    float* recon  = out;
    float* mu     = recon + (size_t)NSAMP * XD;
    float* logvar = mu + (size_t)BATCH * ZS;
    float* zout   = logvar + (size_t)NSAMP * ZD;

    // ws layout (bytes; 1 MiB = 1048576). hd [0,32MiB) overlays everything
    // dead by the time hd_kernel runs; w2t sits above at 32 MiB.
    char* wsb = (char*)d_ws;
    unsigned short* hd   = (unsigned short*)wsb;                          // 32 MiB
    unsigned short* x_bf = (unsigned short*)wsb;                          // 6.25 MiB
    unsigned short* h    = (unsigned short*)(wsb + (size_t)68 * 1048576 / 10);  // ~6.5MiB
    float*          ms   = (float*)(wsb + (size_t)11 * 1048576);          // 18 MiB
    unsigned short* w1t  = (unsigned short*)(wsb + (size_t)295 * 1048576 / 10); // 29.5MiB
    unsigned short* wmst = (unsigned short*)(wsb + (size_t)305 * 1048576 / 10); // 30.5MiB
    unsigned short* w2t  = (unsigned short*)(wsb + (size_t)32 * 1048576);

    // --- prep: transposes / bf16 conversions (independent of each other)
    transpose_bf16<<<dim3(HDIM / 16, KP1 / 16), 256, 0, stream>>>(W1, w1t, XD, HDIM, KP1);
    xpad_kernel<<<(BATCH * 100) / 256, 256, 0, stream>>>(x, x_bf);
    wms_t_kernel<<<dim3(NMS / 16, HDIM / 16), 256, 0, stream>>>(Wmu, Wstd, wmst);
    transpose_bf16<<<dim3(XD / 16, HDIM / 16), 256, 0, stream>>>(Wd2, w2t, HDIM, XD, HDIM);

    // --- encoder on matrix cores
    enc_mfma<1><<<dim3(BATCH / 128, HDIM / 128), 256, 0, stream>>>(
        x_bf, w1t, b1, b1, HDIM, h, HDIM, KP1);
    enc_mfma<0><<<dim3(BATCH / 128, NMS / 128), 256, 0, stream>>>(
        h, wmst, bmu, bstd, ZS, ms, NMS, HDIM);

    // --- sample + logvar (+ mu copy-out)
    sample_kernel<<<(BATCH * ZS) / 256, 256, 0, stream>>>(ms, eps, mu, zout, logvar);

    // --- decoder
    hd_kernel<<<(NSAMP * 128) / 256, 256, 0, stream>>>(zout, Wd1, bd1, hd);
    decoder_mfma<<<dim3(NSAMP / DBM, XD / DBN), 256, 0, stream>>>(hd, w2t, bd2, recon);
}

// Round 4
// 154.638 us; speedup vs baseline: 6.3456x; 1.0012x over previous
//
#include <hip/hip_runtime.h>
#include <hip/hip_bf16.h>
#include <math.h>

#define BATCH 4096
#define XD    784
#define HDIM  512
#define ZD    16
#define NS    8
#define ZS    128
#define NSAMP (BATCH * NS)   // 32768
#define STDN  (ZD * NS * NS) // 1024
#define KP1   800            // K of enc1, padded 784->800 (multiple of 32)
#define NMS   1152           // 128 (mu) + 1024 (std1)

typedef __attribute__((ext_vector_type(8))) short bf16x8;
typedef __attribute__((ext_vector_type(4))) float f32x4;

__device__ inline unsigned short f2bf(float f) {
    unsigned int u = __float_as_uint(f);
    unsigned int r = (u + 0x7fffu + ((u >> 16) & 1u)) >> 16;
    return (unsigned short)r;
}

// ---------------------------------------------------------------------------
// Generic f32->bf16 transpose with K zero-pad: Bt[n][k] (ld=KP) = W[k][n] (ld=N)
// ---------------------------------------------------------------------------
__global__ __launch_bounds__(256)
void transpose_bf16(const float* __restrict__ W, unsigned short* __restrict__ Bt,
                    int K, int N, int KP)
{
    __shared__ unsigned short t[16][17];
    const int tx = threadIdx.x & 15;
    const int ty = threadIdx.x >> 4;
    const int n = blockIdx.x * 16 + tx;
    const int k = blockIdx.y * 16 + ty;
    t[ty][tx] = (k < K) ? f2bf(W[(size_t)k * N + n]) : (unsigned short)0;
    __syncthreads();
    const int on = blockIdx.x * 16 + ty;
    const int ok = blockIdx.y * 16 + tx;
    Bt[(size_t)on * KP + ok] = t[tx][ty];
}

// ---------------------------------------------------------------------------
// wmst[1152][512] bf16: rows 0..127 = Wmu^T, rows 128..1151 = Wstd^T
// ---------------------------------------------------------------------------
__global__ __launch_bounds__(256)
void wms_t_kernel(const float* __restrict__ Wmu, const float* __restrict__ Wstd,
                  unsigned short* __restrict__ Bt)
{
    __shared__ unsigned short t[16][17];
    const int tx = threadIdx.x & 15;
    const int ty = threadIdx.x >> 4;
    const int n = blockIdx.x * 16 + tx;
    const int k = blockIdx.y * 16 + ty;
    const float v = (n < ZS) ? Wmu[(size_t)k * ZS + n]
                             : Wstd[(size_t)k * STDN + (n - ZS)];
    t[ty][tx] = f2bf(v);
    __syncthreads();
    const int on = blockIdx.x * 16 + ty;
    const int ok = blockIdx.y * 16 + tx;
    Bt[(size_t)on * HDIM + ok] = t[tx][ty];
}

// ---------------------------------------------------------------------------
// x [4096][784] f32 -> xb [4096][800] bf16 (zero pad).
// ---------------------------------------------------------------------------
__global__ __launch_bounds__(256)
void xpad_kernel(const float* __restrict__ x, unsigned short* __restrict__ xb)
{
    const int idx = blockIdx.x * 256 + threadIdx.x;
    const int row = idx / 100;
    const int c8 = idx - row * 100;
    const int k0 = c8 * 8;
    ushort4 o0 = {0, 0, 0, 0}, o1 = {0, 0, 0, 0};
    if (k0 < XD) {
        const float4 a = *reinterpret_cast<const float4*>(&x[(size_t)row * XD + k0]);
        const float4 b = *reinterpret_cast<const float4*>(&x[(size_t)row * XD + k0 + 4]);
        o0.x = f2bf(a.x); o0.y = f2bf(a.y); o0.z = f2bf(a.z); o0.w = f2bf(a.w);
        o1.x = f2bf(b.x); o1.y = f2bf(b.y); o1.z = f2bf(b.z); o1.w = f2bf(b.w);
    }
    *reinterpret_cast<ushort4*>(&xb[(size_t)row * KP1 + k0]) = o0;
    *reinterpret_cast<ushort4*>(&xb[(size_t)row * KP1 + k0 + 4]) = o1;
}

// ---------------------------------------------------------------------------
// Encoder MFMA GEMM (unchanged from R3): out = [relu](A @ Bt^T + bias).
// ---------------------------------------------------------------------------
#define ELPAD 40

template<int OUT_BF16>
__global__ __launch_bounds__(256)
void enc_mfma(const unsigned short* __restrict__ A,
              const unsigned short* __restrict__ Bt,
              const float* __restrict__ bias0, const float* __restrict__ bias1,
              int bsplit, void* __restrict__ Cout, int ldc, int K)
{
    __shared__ __align__(16) unsigned short Al[2][128][ELPAD];
    __shared__ __align__(16) unsigned short Bl[2][128][ELPAD];

    const int tid = threadIdx.x;
    const int m0 = blockIdx.x * 128;
    const int n0 = blockIdx.y * 128;
    const int wave = tid >> 6;
    const int lane = tid & 63;
    const int lr = lane & 15;
    const int kg = lane >> 4;
    const int nkt = K >> 5;

    f32x4 acc[2][8];
    #pragma unroll
    for (int i = 0; i < 2; ++i)
        #pragma unroll
        for (int j = 0; j < 8; ++j)
            acc[i][j] = (f32x4){0.f, 0.f, 0.f, 0.f};

    {
        const int r = tid >> 2, ks = tid & 3;
        *reinterpret_cast<int4*>(&Al[0][r][ks * 8]) =
            *reinterpret_cast<const int4*>(&A[(size_t)(m0 + r) * K + ks * 8]);
        *reinterpret_cast<int4*>(&Al[0][r + 64][ks * 8]) =
            *reinterpret_cast<const int4*>(&A[(size_t)(m0 + r + 64) * K + ks * 8]);
        *reinterpret_cast<int4*>(&Bl[0][r][ks * 8]) =
            *reinterpret_cast<const int4*>(&Bt[(size_t)(n0 + r) * K + ks * 8]);
        *reinterpret_cast<int4*>(&Bl[0][r + 64][ks * 8]) =
            *reinterpret_cast<const int4*>(&Bt[(size_t)(n0 + r + 64) * K + ks * 8]);
    }
    __syncthreads();

    int buf = 0;
    for (int kt = 0; kt < nkt; ++kt) {
        int4 sa0, sa1, sb0, sb1;
        const bool pf = (kt + 1 < nkt);
        const int r = tid >> 2, ks = tid & 3;
        if (pf) {
            const int k0 = (kt + 1) * 32 + ks * 8;
            sa0 = *reinterpret_cast<const int4*>(&A[(size_t)(m0 + r) * K + k0]);
            sa1 = *reinterpret_cast<const int4*>(&A[(size_t)(m0 + r + 64) * K + k0]);
            sb0 = *reinterpret_cast<const int4*>(&Bt[(size_t)(n0 + r) * K + k0]);
            sb1 = *reinterpret_cast<const int4*>(&Bt[(size_t)(n0 + r + 64) * K + k0]);
        }

        bf16x8 af[2], bfr[8];
        #pragma unroll
        for (int mi = 0; mi < 2; ++mi)
            af[mi] = *reinterpret_cast<const bf16x8*>(&Al[buf][wave * 32 + mi * 16 + lr][kg * 8]);
        #pragma unroll
        for (int nf = 0; nf < 8; ++nf)
            bfr[nf] = *reinterpret_cast<const bf16x8*>(&Bl[buf][nf * 16 + lr][kg * 8]);
        #pragma unroll
        for (int mi = 0; mi < 2; ++mi)
            #pragma unroll
            for (int nf = 0; nf < 8; ++nf)
                acc[mi][nf] = __builtin_amdgcn_mfma_f32_16x16x32_bf16(af[mi], bfr[nf], acc[mi][nf], 0, 0, 0);

        if (pf) {
            const int nb = buf ^ 1;
            *reinterpret_cast<int4*>(&Al[nb][r][ks * 8]) = sa0;
            *reinterpret_cast<int4*>(&Al[nb][r + 64][ks * 8]) = sa1;
            *reinterpret_cast<int4*>(&Bl[nb][r][ks * 8]) = sb0;
            *reinterpret_cast<int4*>(&Bl[nb][r + 64][ks * 8]) = sb1;
        }
        __syncthreads();
        buf ^= 1;
    }

    const int mrow = m0 + wave * 32;
    #pragma unroll
    for (int nf = 0; nf < 8; ++nf) {
        const int col = n0 + nf * 16 + lr;
        const float bb = (col < bsplit) ? bias0[col] : bias1[col - bsplit];
        #pragma unroll
        for (int mi = 0; mi < 2; ++mi) {
            #pragma unroll
            for (int j = 0; j < 4; ++j) {
                const int row = mrow + mi * 16 + kg * 4 + j;
                const float v = acc[mi][nf][j] + bb;
                if (OUT_BF16)
                    ((unsigned short*)Cout)[(size_t)row * ldc + col] = f2bf(fmaxf(v, 0.f));
                else
                    ((float*)Cout)[(size_t)row * ldc + col] = v;
            }
        }
    }
}

// ---------------------------------------------------------------------------
// Sparse sample (unchanged).
// ---------------------------------------------------------------------------
__global__ __launch_bounds__(256)
void sample_kernel(const float* __restrict__ ms, const float* __restrict__ eps,
                   float* __restrict__ mu_out,
                   float* __restrict__ z_out, float* __restrict__ logvar_out)
{
    const int idx = blockIdx.x * 256 + threadIdx.x;
    const int b = idx >> 7;
    const int r = idx & 127;
    const int d = r & 15;
    const int s1 = r >> 4;

    const float* v = &ms[(size_t)b * NMS + ZS + r * NS];
    const float* e = &eps[(size_t)b * ZS + d];
    float zacc = 0.f, dacc = 0.f;
    #pragma unroll
    for (int k = 0; k < NS; ++k) {
        const float vv = v[k];
        zacc += vv * e[16 * k];
        dacc += vv * vv;
    }
    const float muv = ms[(size_t)b * NMS + r];
    mu_out[(size_t)b * ZS + r] = muv;
    const float zv = muv + zacc;
    const size_t orow = (size_t)(b * NS + s1) * ZD + d;
    z_out[orow] = zv;
    logvar_out[orow] = logf(dacc);
}

// ---------------------------------------------------------------------------
// hd = relu(z @ Wd1 + bd1) in bf16 (unchanged).
// ---------------------------------------------------------------------------
__global__ __launch_bounds__(256)
void hd_kernel(const float* __restrict__ z, const float* __restrict__ Wd1,
               const float* __restrict__ bd1, unsigned short* __restrict__ hd)
{
    const int idx = blockIdx.x * 256 + threadIdx.x;
    const int m = idx >> 7;
    const int n0 = (idx & 127) * 4;
    const float* zr = &z[(size_t)m * ZD];
    float4 a = *reinterpret_cast<const float4*>(&bd1[n0]);
    #pragma unroll
    for (int k = 0; k < ZD; ++k) {
        const float zk = zr[k];
        float4 w = *reinterpret_cast<const float4*>(&Wd1[(size_t)k * HDIM + n0]);
        a.x += zk * w.x; a.y += zk * w.y; a.z += zk * w.z; a.w += zk * w.w;
    }
    ushort4 o;
    o.x = f2bf(fmaxf(a.x, 0.f));
    o.y = f2bf(fmaxf(a.y, 0.f));
    o.z = f2bf(fmaxf(a.z, 0.f));
    o.w = f2bf(fmaxf(a.w, 0.f));
    *reinterpret_cast<ushort4*>(&hd[(size_t)m * HDIM + n0]) = o;
}

// ---------------------------------------------------------------------------
// Decoder GEMM via MFMA: recon = sigmoid(hd @ Wd2 + bd2)
// M=32768, N=784, K=512. BM=256, BN=112, BK=32. 4 waves along M,
// per-wave 64x112 (acc[4][7]) -> 40.7 FLOP per LDS byte (MFMA-bound).
// ---------------------------------------------------------------------------
#define DBM 256
#define DBN 112
#define DNKT 16
#define LPAD 40

__global__ __launch_bounds__(256)
void decoder_mfma(const unsigned short* __restrict__ hd,
                  const unsigned short* __restrict__ w2t,
                  const float* __restrict__ bd2,
                  float* __restrict__ recon)
{
    __shared__ __align__(16) unsigned short Al[2][DBM][LPAD];   // 40960 B
    __shared__ __align__(16) unsigned short Bl[2][DBN][LPAD];   // 17920 B

    const int tid = threadIdx.x;
    const int m0 = blockIdx.x * DBM;
    const int n0 = blockIdx.y * DBN;
    const int wave = tid >> 6;
    const int lane = tid & 63;
    const int lr = lane & 15;
    const int kg = lane >> 4;

    f32x4 acc[4][7];
    #pragma unroll
    for (int i = 0; i < 4; ++i)
        #pragma unroll
        for (int j = 0; j < 7; ++j)
            acc[i][j] = (f32x4){0.f, 0.f, 0.f, 0.f};

    // prologue: stage kt=0 into buffer 0
    {
        const int r = tid >> 2, ks = (tid & 3) * 8;
        #pragma unroll
        for (int q = 0; q < 4; ++q)
            *reinterpret_cast<int4*>(&Al[0][r + q * 64][ks]) =
                *reinterpret_cast<const int4*>(&hd[(size_t)(m0 + r + q * 64) * HDIM + ks]);
        *reinterpret_cast<int4*>(&Bl[0][r][ks]) =
            *reinterpret_cast<const int4*>(&w2t[(size_t)(n0 + r) * HDIM + ks]);
        if (tid < 192)
            *reinterpret_cast<int4*>(&Bl[0][r + 64][ks]) =
                *reinterpret_cast<const int4*>(&w2t[(size_t)(n0 + r + 64) * HDIM + ks]);
    }
    __syncthreads();

    int buf = 0;
    for (int kt = 0; kt < DNKT; ++kt) {
        int4 sa[4], sb0, sb1;
        const bool pf = (kt + 1 < DNKT);
        const int r = tid >> 2, ks = (tid & 3) * 8;
        if (pf) {
            const int k0 = (kt + 1) * 32 + ks;
            #pragma unroll
            for (int q = 0; q < 4; ++q)
                sa[q] = *reinterpret_cast<const int4*>(&hd[(size_t)(m0 + r + q * 64) * HDIM + k0]);
            sb0 = *reinterpret_cast<const int4*>(&w2t[(size_t)(n0 + r) * HDIM + k0]);
            if (tid < 192)
                sb1 = *reinterpret_cast<const int4*>(&w2t[(size_t)(n0 + r + 64) * HDIM + k0]);
        }

        bf16x8 af[4], bfr[7];
        #pragma unroll
        for (int mi = 0; mi < 4; ++mi)
            af[mi] = *reinterpret_cast<const bf16x8*>(&Al[buf][wave * 64 + mi * 16 + lr][kg * 8]);
        #pragma unroll
        for (int nf = 0; nf < 7; ++nf)
            bfr[nf] = *reinterpret_cast<const bf16x8*>(&Bl[buf][nf * 16 + lr][kg * 8]);
        #pragma unroll
        for (int mi = 0; mi < 4; ++mi)
            #pragma unroll
            for (int nf = 0; nf < 7; ++nf)
                acc[mi][nf] = __builtin_amdgcn_mfma_f32_16x16x32_bf16(af[mi], bfr[nf], acc[mi][nf], 0, 0, 0);

        if (pf) {
            const int nb = buf ^ 1;
            #pragma unroll
            for (int q = 0; q < 4; ++q)
                *reinterpret_cast<int4*>(&Al[nb][r + q * 64][ks]) = sa[q];
            *reinterpret_cast<int4*>(&Bl[nb][r][ks]) = sb0;
            if (tid < 192)
                *reinterpret_cast<int4*>(&Bl[nb][r + 64][ks]) = sb1;
        }
        __syncthreads();
        buf ^= 1;
    }

    // epilogue: bias + sigmoid, f32 store
    const int mrow = m0 + wave * 64;
    #pragma unroll
    for (int nf = 0; nf < 7; ++nf) {
        const int col = n0 + nf * 16 + lr;
        const float bias = bd2[col];
        #pragma unroll
        for (int mi = 0; mi < 4; ++mi) {
            #pragma unroll
            for (int j = 0; j < 4; ++j) {
                const int row = mrow + mi * 16 + kg * 4 + j;
                const float v = acc[mi][nf][j] + bias;
                recon[(size_t)row * XD + col] = 1.f / (1.f + __expf(-v));
            }
        }
    }
}

// ---------------------------------------------------------------------------
extern "C" void kernel_launch(void* const* d_in, const int* in_sizes, int n_in,
                              void* d_out, int out_size, void* d_ws, size_t ws_size,
                              hipStream_t stream)
{
    const float* x    = (const float*)d_in[0];
    const float* eps  = (const float*)d_in[1];
    const float* W1   = (const float*)d_in[2];
    const float* b1   = (const float*)d_in[3];
    const float* Wmu  = (const float*)d_in[4];
    const float* bmu  = (const float*)d_in[5];
    const float* Wstd = (const float*)d_in[6];
    const float* bstd = (const float*)d_in[7];
    const float* Wd1  = (const float*)d_in[8];
    const float* bd1  = (const float*)d_in[9];
    const float* Wd2  = (const float*)d_in[10];
    const float* bd2  = (const float*)d_in[11];

    float* out    = (float*)d_out;
    float* recon  = out;
    float* mu     = recon + (size_t)NSAMP * XD;
    float* logvar = mu + (size_t)BATCH * ZS;
    float* zout   = logvar + (size_t)NSAMP * ZD;

    char* wsb = (char*)d_ws;
    unsigned short* hd   = (unsigned short*)wsb;                          // 32 MiB
    unsigned short* x_bf = (unsigned short*)wsb;                          // 6.25 MiB
    unsigned short* h    = (unsigned short*)(wsb + (size_t)68 * 1048576 / 10);
    float*          ms   = (float*)(wsb + (size_t)11 * 1048576);
    unsigned short* w1t  = (unsigned short*)(wsb + (size_t)295 * 1048576 / 10);
    unsigned short* wmst = (unsigned short*)(wsb + (size_t)305 * 1048576 / 10);
    unsigned short* w2t  = (unsigned short*)(wsb + (size_t)32 * 1048576);

    transpose_bf16<<<dim3(HDIM / 16, KP1 / 16), 256, 0, stream>>>(W1, w1t, XD, HDIM, KP1);
    xpad_kernel<<<(BATCH * 100) / 256, 256, 0, stream>>>(x, x_bf);
    wms_t_kernel<<<dim3(NMS / 16, HDIM / 16), 256, 0, stream>>>(Wmu, Wstd, wmst);
    transpose_bf16<<<dim3(XD / 16, HDIM / 16), 256, 0, stream>>>(Wd2, w2t, HDIM, XD, HDIM);

    enc_mfma<1><<<dim3(BATCH / 128, HDIM / 128), 256, 0, stream>>>(
        x_bf, w1t, b1, b1, HDIM, h, HDIM, KP1);
    enc_mfma<0><<<dim3(BATCH / 128, NMS / 128), 256, 0, stream>>>(
        h, wmst, bmu, bstd, ZS, ms, NMS, HDIM);

    sample_kernel<<<(BATCH * ZS) / 256, 256, 0, stream>>>(ms, eps, mu, zout, logvar);

    hd_kernel<<<(NSAMP * 128) / 256, 256, 0, stream>>>(zout, Wd1, bd1, hd);
    decoder_mfma<<<dim3(NSAMP / DBM, XD / DBN), 256, 0, stream>>>(hd, w2t, bd2, recon);
}

// Round 6
// 150.859 us; speedup vs baseline: 6.5046x; 1.0251x over previous
//
#include <hip/hip_runtime.h>
#include <hip/hip_bf16.h>
#include <math.h>

#define BATCH 4096
#define XD    784
#define HDIM  512
#define ZD    16
#define NS    8
#define ZS    128
#define NSAMP (BATCH * NS)   // 32768
#define STDN  (ZD * NS * NS) // 1024
#define KP1   800            // K of enc1, padded 784->800
#define NMS   1152           // 128 (mu) + 1024 (std1)
#define NP2   800            // w2t rows padded 784->800 (5*160)

typedef __attribute__((ext_vector_type(8))) short bf16x8;
typedef __attribute__((ext_vector_type(4))) float f32x4;

__device__ inline unsigned short f2bf(float f) {
    unsigned int u = __float_as_uint(f);
    unsigned int r = (u + 0x7fffu + ((u >> 16) & 1u)) >> 16;
    return (unsigned short)r;
}

// ---------------------------------------------------------------------------
// Merged prep: block ranges
//   [0,1600)    : W1^T   -> w1t [512][800]
//   [1600,3200) : xpad   -> x_bf [4096][800]
//   [3200,5504) : [Wmu|Wstd]^T -> wmst [1152][512]
//   [5504,7104) : Wd2^T  -> w2tp [800][512] (rows>=784 zero)
// ---------------------------------------------------------------------------
__global__ __launch_bounds__(256)
void prep_kernel(const float* __restrict__ W1, const float* __restrict__ x,
                 const float* __restrict__ Wmu, const float* __restrict__ Wstd,
                 const float* __restrict__ Wd2,
                 unsigned short* __restrict__ w1t, unsigned short* __restrict__ x_bf,
                 unsigned short* __restrict__ wmst, unsigned short* __restrict__ w2tp)
{
    __shared__ unsigned short t[16][17];
    const int tid = threadIdx.x;
    const int tx = tid & 15, ty = tid >> 4;
    const int bid = blockIdx.x;

    if (bid < 1600) {                      // W1^T (K=784 -> 800, N=512)
        const int bx = bid & 31, by = bid >> 5;        // 32 x 50
        const int n = bx * 16 + tx, k = by * 16 + ty;
        t[ty][tx] = (k < XD) ? f2bf(W1[(size_t)k * HDIM + n]) : (unsigned short)0;
        __syncthreads();
        w1t[(size_t)(bx * 16 + ty) * KP1 + (by * 16 + tx)] = t[tx][ty];
    } else if (bid < 3200) {               // xpad
        const int idx = (bid - 1600) * 256 + tid;
        const int row = idx / 100;
        const int c8 = idx - row * 100;
        const int k0 = c8 * 8;
        ushort4 o0 = {0, 0, 0, 0}, o1 = {0, 0, 0, 0};
        if (k0 < XD) {
            const float4 a = *reinterpret_cast<const float4*>(&x[(size_t)row * XD + k0]);
            const float4 b = *reinterpret_cast<const float4*>(&x[(size_t)row * XD + k0 + 4]);
            o0.x = f2bf(a.x); o0.y = f2bf(a.y); o0.z = f2bf(a.z); o0.w = f2bf(a.w);
            o1.x = f2bf(b.x); o1.y = f2bf(b.y); o1.z = f2bf(b.z); o1.w = f2bf(b.w);
        }
        *reinterpret_cast<ushort4*>(&x_bf[(size_t)row * KP1 + k0]) = o0;
        *reinterpret_cast<ushort4*>(&x_bf[(size_t)row * KP1 + k0 + 4]) = o1;
    } else if (bid < 5504) {               // [Wmu|Wstd]^T (N=1152, K=512)
        const int b = bid - 3200;                      // 72 x 32
        const int bx = b % 72, by = b / 72;
        const int n = bx * 16 + tx, k = by * 16 + ty;
        const float v = (n < ZS) ? Wmu[(size_t)k * ZS + n]
                                 : Wstd[(size_t)k * STDN + (n - ZS)];
        t[ty][tx] = f2bf(v);
        __syncthreads();
        wmst[(size_t)(bx * 16 + ty) * HDIM + (by * 16 + tx)] = t[tx][ty];
    } else {                               // Wd2^T (N=784 -> 800 rows, K=512)
        const int b = bid - 5504;                      // 50 x 32
        const int bx = b % 50, by = b / 50;
        const int n = bx * 16 + tx, k = by * 16 + ty;
        t[ty][tx] = (n < XD) ? f2bf(Wd2[(size_t)k * XD + n]) : (unsigned short)0;
        __syncthreads();
        w2tp[(size_t)(bx * 16 + ty) * HDIM + (by * 16 + tx)] = t[tx][ty];
    }
}

// ---------------------------------------------------------------------------
// Encoder MFMA GEMM (unchanged, proven): out = [relu](A @ Bt^T + bias).
// ---------------------------------------------------------------------------
template<int OUT_BF16>
__global__ __launch_bounds__(256)
void enc_mfma(const unsigned short* __restrict__ A,
              const unsigned short* __restrict__ Bt,
              const float* __restrict__ bias0, const float* __restrict__ bias1,
              int bsplit, void* __restrict__ Cout, int ldc, int K)
{
    __shared__ __align__(16) unsigned short Al[2][128][40];
    __shared__ __align__(16) unsigned short Bl[2][128][40];

    const int tid = threadIdx.x;
    const int m0 = blockIdx.x * 128;
    const int n0 = blockIdx.y * 128;
    const int wave = tid >> 6;
    const int lane = tid & 63;
    const int lr = lane & 15;
    const int kg = lane >> 4;
    const int nkt = K >> 5;

    f32x4 acc[2][8];
    #pragma unroll
    for (int i = 0; i < 2; ++i)
        #pragma unroll
        for (int j = 0; j < 8; ++j)
            acc[i][j] = (f32x4){0.f, 0.f, 0.f, 0.f};

    {
        const int r = tid >> 2, ks = tid & 3;
        *reinterpret_cast<int4*>(&Al[0][r][ks * 8]) =
            *reinterpret_cast<const int4*>(&A[(size_t)(m0 + r) * K + ks * 8]);
        *reinterpret_cast<int4*>(&Al[0][r + 64][ks * 8]) =
            *reinterpret_cast<const int4*>(&A[(size_t)(m0 + r + 64) * K + ks * 8]);
        *reinterpret_cast<int4*>(&Bl[0][r][ks * 8]) =
            *reinterpret_cast<const int4*>(&Bt[(size_t)(n0 + r) * K + ks * 8]);
        *reinterpret_cast<int4*>(&Bl[0][r + 64][ks * 8]) =
            *reinterpret_cast<const int4*>(&Bt[(size_t)(n0 + r + 64) * K + ks * 8]);
    }
    __syncthreads();

    int buf = 0;
    for (int kt = 0; kt < nkt; ++kt) {
        int4 sa0, sa1, sb0, sb1;
        const bool pf = (kt + 1 < nkt);
        const int r = tid >> 2, ks = tid & 3;
        if (pf) {
            const int k0 = (kt + 1) * 32 + ks * 8;
            sa0 = *reinterpret_cast<const int4*>(&A[(size_t)(m0 + r) * K + k0]);
            sa1 = *reinterpret_cast<const int4*>(&A[(size_t)(m0 + r + 64) * K + k0]);
            sb0 = *reinterpret_cast<const int4*>(&Bt[(size_t)(n0 + r) * K + k0]);
            sb1 = *reinterpret_cast<const int4*>(&Bt[(size_t)(n0 + r + 64) * K + k0]);
        }

        bf16x8 af[2], bfr[8];
        #pragma unroll
        for (int mi = 0; mi < 2; ++mi)
            af[mi] = *reinterpret_cast<const bf16x8*>(&Al[buf][wave * 32 + mi * 16 + lr][kg * 8]);
        #pragma unroll
        for (int nf = 0; nf < 8; ++nf)
            bfr[nf] = *reinterpret_cast<const bf16x8*>(&Bl[buf][nf * 16 + lr][kg * 8]);
        #pragma unroll
        for (int mi = 0; mi < 2; ++mi)
            #pragma unroll
            for (int nf = 0; nf < 8; ++nf)
                acc[mi][nf] = __builtin_amdgcn_mfma_f32_16x16x32_bf16(af[mi], bfr[nf], acc[mi][nf], 0, 0, 0);

        if (pf) {
            const int nb = buf ^ 1;
            *reinterpret_cast<int4*>(&Al[nb][r][ks * 8]) = sa0;
            *reinterpret_cast<int4*>(&Al[nb][r + 64][ks * 8]) = sa1;
            *reinterpret_cast<int4*>(&Bl[nb][r][ks * 8]) = sb0;
            *reinterpret_cast<int4*>(&Bl[nb][r + 64][ks * 8]) = sb1;
        }
        __syncthreads();
        buf ^= 1;
    }

    const int mrow = m0 + wave * 32;
    #pragma unroll
    for (int nf = 0; nf < 8; ++nf) {
        const int col = n0 + nf * 16 + lr;
        const float bb = (col < bsplit) ? bias0[col] : bias1[col - bsplit];
        #pragma unroll
        for (int mi = 0; mi < 2; ++mi) {
            #pragma unroll
            for (int j = 0; j < 4; ++j) {
                const int row = mrow + mi * 16 + kg * 4 + j;
                const float v = acc[mi][nf][j] + bb;
                if (OUT_BF16)
                    ((unsigned short*)Cout)[(size_t)row * ldc + col] = f2bf(fmaxf(v, 0.f));
                else
                    ((float*)Cout)[(size_t)row * ldc + col] = v;
            }
        }
    }
}

// ---------------------------------------------------------------------------
// Sparse sample (unchanged).
// ---------------------------------------------------------------------------
__global__ __launch_bounds__(256)
void sample_kernel(const float* __restrict__ ms, const float* __restrict__ eps,
                   float* __restrict__ mu_out,
                   float* __restrict__ z_out, float* __restrict__ logvar_out)
{
    const int idx = blockIdx.x * 256 + threadIdx.x;
    const int b = idx >> 7;
    const int r = idx & 127;
    const int d = r & 15;
    const int s1 = r >> 4;

    const float* v = &ms[(size_t)b * NMS + ZS + r * NS];
    const float* e = &eps[(size_t)b * ZS + d];
    float zacc = 0.f, dacc = 0.f;
    #pragma unroll
    for (int k = 0; k < NS; ++k) {
        const float vv = v[k];
        zacc += vv * e[16 * k];
        dacc += vv * vv;
    }
    const float muv = ms[(size_t)b * NMS + r];
    mu_out[(size_t)b * ZS + r] = muv;
    const float zv = muv + zacc;
    const size_t orow = (size_t)(b * NS + s1) * ZD + d;
    z_out[orow] = zv;
    logvar_out[orow] = logf(dacc);
}

// ---------------------------------------------------------------------------
// hd = relu(z @ Wd1 + bd1) in bf16 (unchanged).
// ---------------------------------------------------------------------------
__global__ __launch_bounds__(256)
void hd_kernel(const float* __restrict__ z, const float* __restrict__ Wd1,
               const float* __restrict__ bd1, unsigned short* __restrict__ hd)
{
    const int idx = blockIdx.x * 256 + threadIdx.x;
    const int m = idx >> 7;
    const int n0 = (idx & 127) * 4;
    const float* zr = &z[(size_t)m * ZD];
    float4 a = *reinterpret_cast<const float4*>(&bd1[n0]);
    #pragma unroll
    for (int k = 0; k < ZD; ++k) {
        const float zk = zr[k];
        float4 w = *reinterpret_cast<const float4*>(&Wd1[(size_t)k * HDIM + n0]);
        a.x += zk * w.x; a.y += zk * w.y; a.z += zk * w.z; a.w += zk * w.w;
    }
    ushort4 o;
    o.x = f2bf(fmaxf(a.x, 0.f));
    o.y = f2bf(fmaxf(a.y, 0.f));
    o.z = f2bf(fmaxf(a.z, 0.f));
    o.w = f2bf(fmaxf(a.w, 0.f));
    *reinterpret_cast<ushort4*>(&hd[(size_t)m * HDIM + n0]) = o;
}

// ---------------------------------------------------------------------------
// Decoder GEMM via MFMA: recon = sigmoid(hd @ Wd2 + bd2)
// M=32768, N=784 (->800 padded), K=512. BM=128, BN=160, BK=32.
// 4 waves as 2x2 (each 64x80, acc[4][5]). LDS 46 KB -> 3 blocks/CU.
// B staging: 640 int4 loads = 256 (rows 0-63) + 256 (rows 64-127) + 128 (rows 128-159).
// ---------------------------------------------------------------------------
#define DBM 128
#define DBN 160
#define DNKT 16

__global__ __launch_bounds__(256)
void decoder_mfma(const unsigned short* __restrict__ hd,
                  const unsigned short* __restrict__ w2tp,
                  const float* __restrict__ bd2,
                  float* __restrict__ recon)
{
    __shared__ __align__(16) unsigned short Al[2][DBM][40];   // 20480 B
    __shared__ __align__(16) unsigned short Bl[2][DBN][40];   // 25600 B

    const int tid = threadIdx.x;
    const int m0 = blockIdx.x * DBM;
    const int n0 = blockIdx.y * DBN;
    const int wave = tid >> 6;
    const int wr = wave >> 1;
    const int wc = wave & 1;
    const int lane = tid & 63;
    const int lr = lane & 15;
    const int kg = lane >> 4;

    // staging coordinates
    const int r = tid >> 2,               ks  = (tid & 3) * 8;          // rows 0..63
    const int r1 = ((tid + 256) >> 2),    ks1 = (((tid + 256) & 3)) * 8; // rows 64..127
    const int r2 = ((tid + 512) >> 2),    ks2 = (((tid + 512) & 3)) * 8; // rows 128..159

    f32x4 acc[4][5];
    #pragma unroll
    for (int i = 0; i < 4; ++i)
        #pragma unroll
        for (int j = 0; j < 5; ++j)
            acc[i][j] = (f32x4){0.f, 0.f, 0.f, 0.f};

    // prologue: stage kt=0 into buffer 0
    {
        *reinterpret_cast<int4*>(&Al[0][r][ks]) =
            *reinterpret_cast<const int4*>(&hd[(size_t)(m0 + r) * HDIM + ks]);
        *reinterpret_cast<int4*>(&Al[0][r1][ks1]) =
            *reinterpret_cast<const int4*>(&hd[(size_t)(m0 + r1) * HDIM + ks1]);
        *reinterpret_cast<int4*>(&Bl[0][r][ks]) =
            *reinterpret_cast<const int4*>(&w2tp[(size_t)(n0 + r) * HDIM + ks]);
        *reinterpret_cast<int4*>(&Bl[0][r1][ks1]) =
            *reinterpret_cast<const int4*>(&w2tp[(size_t)(n0 + r1) * HDIM + ks1]);
        if (tid < 128)
            *reinterpret_cast<int4*>(&Bl[0][r2][ks2]) =
                *reinterpret_cast<const int4*>(&w2tp[(size_t)(n0 + r2) * HDIM + ks2]);
    }
    __syncthreads();

    int buf = 0;
    for (int kt = 0; kt < DNKT; ++kt) {
        int4 sa0, sa1, sb0, sb1, sb2;
        const bool pf = (kt + 1 < DNKT);
        if (pf) {
            const int k0 = (kt + 1) * 32;
            sa0 = *reinterpret_cast<const int4*>(&hd[(size_t)(m0 + r) * HDIM + k0 + ks]);
            sa1 = *reinterpret_cast<const int4*>(&hd[(size_t)(m0 + r1) * HDIM + k0 + ks1]);
            sb0 = *reinterpret_cast<const int4*>(&w2tp[(size_t)(n0 + r) * HDIM + k0 + ks]);
            sb1 = *reinterpret_cast<const int4*>(&w2tp[(size_t)(n0 + r1) * HDIM + k0 + ks1]);
            if (tid < 128)
                sb2 = *reinterpret_cast<const int4*>(&w2tp[(size_t)(n0 + r2) * HDIM + k0 + ks2]);
        }

        bf16x8 af[4], bfr[5];
        #pragma unroll
        for (int mi = 0; mi < 4; ++mi)
            af[mi] = *reinterpret_cast<const bf16x8*>(&Al[buf][wr * 64 + mi * 16 + lr][kg * 8]);
        #pragma unroll
        for (int nf = 0; nf < 5; ++nf)
            bfr[nf] = *reinterpret_cast<const bf16x8*>(&Bl[buf][wc * 80 + nf * 16 + lr][kg * 8]);
        #pragma unroll
        for (int mi = 0; mi < 4; ++mi)
            #pragma unroll
            for (int nf = 0; nf < 5; ++nf)
                acc[mi][nf] = __builtin_amdgcn_mfma_f32_16x16x32_bf16(af[mi], bfr[nf], acc[mi][nf], 0, 0, 0);

        if (pf) {
            const int nb = buf ^ 1;
            *reinterpret_cast<int4*>(&Al[nb][r][ks]) = sa0;
            *reinterpret_cast<int4*>(&Al[nb][r1][ks1]) = sa1;
            *reinterpret_cast<int4*>(&Bl[nb][r][ks]) = sb0;
            *reinterpret_cast<int4*>(&Bl[nb][r1][ks1]) = sb1;
            if (tid < 128)
                *reinterpret_cast<int4*>(&Bl[nb][r2][ks2]) = sb2;
        }
        __syncthreads();
        buf ^= 1;
    }

    // epilogue: bias + sigmoid, guarded f32 store
    const int mrow = m0 + wr * 64;
    #pragma unroll
    for (int nf = 0; nf < 5; ++nf) {
        const int col = n0 + wc * 80 + nf * 16 + lr;
        if (col < XD) {
            const float bias = bd2[col];
            #pragma unroll
            for (int mi = 0; mi < 4; ++mi) {
                #pragma unroll
                for (int j = 0; j < 4; ++j) {
                    const int row = mrow + mi * 16 + kg * 4 + j;
                    const float v = acc[mi][nf][j] + bias;
                    recon[(size_t)row * XD + col] = 1.f / (1.f + __expf(-v));
                }
            }
        }
    }
}

// ---------------------------------------------------------------------------
extern "C" void kernel_launch(void* const* d_in, const int* in_sizes, int n_in,
                              void* d_out, int out_size, void* d_ws, size_t ws_size,
                              hipStream_t stream)
{
    const float* x    = (const float*)d_in[0];
    const float* eps  = (const float*)d_in[1];
    const float* W1   = (const float*)d_in[2];
    const float* b1   = (const float*)d_in[3];
    const float* Wmu  = (const float*)d_in[4];
    const float* bmu  = (const float*)d_in[5];
    const float* Wstd = (const float*)d_in[6];
    const float* bstd = (const float*)d_in[7];
    const float* Wd1  = (const float*)d_in[8];
    const float* bd1  = (const float*)d_in[9];
    const float* Wd2  = (const float*)d_in[10];
    const float* bd2  = (const float*)d_in[11];

    float* out    = (float*)d_out;
    float* recon  = out;
    float* mu     = recon + (size_t)NSAMP * XD;
    float* logvar = mu + (size_t)BATCH * ZS;
    float* zout   = logvar + (size_t)NSAMP * ZD;

    char* wsb = (char*)d_ws;
    unsigned short* hd   = (unsigned short*)wsb;                            // 32 MiB
    unsigned short* x_bf = (unsigned short*)wsb;                            // 6.25 MiB
    unsigned short* h    = (unsigned short*)(wsb + (size_t)68 * 1048576 / 10);
    float*          ms   = (float*)(wsb + (size_t)11 * 1048576);
    unsigned short* w1t  = (unsigned short*)(wsb + (size_t)295 * 1048576 / 10);
    unsigned short* wmst = (unsigned short*)(wsb + (size_t)305 * 1048576 / 10);
    unsigned short* w2tp = (unsigned short*)(wsb + (size_t)32 * 1048576);   // 800x512 bf16

    prep_kernel<<<7104, 256, 0, stream>>>(W1, x, Wmu, Wstd, Wd2, w1t, x_bf, wmst, w2tp);

    enc_mfma<1><<<dim3(BATCH / 128, HDIM / 128), 256, 0, stream>>>(
        x_bf, w1t, b1, b1, HDIM, h, HDIM, KP1);
    enc_mfma<0><<<dim3(BATCH / 128, NMS / 128), 256, 0, stream>>>(
        h, wmst, bmu, bstd, ZS, ms, NMS, HDIM);

    sample_kernel<<<(BATCH * ZS) / 256, 256, 0, stream>>>(ms, eps, mu, zout, logvar);

    hd_kernel<<<(NSAMP * 128) / 256, 256, 0, stream>>>(zout, Wd1, bd1, hd);
    decoder_mfma<<<dim3(NSAMP / DBM, NP2 / DBN), 256, 0, stream>>>(hd, w2tp, bd2, recon);
}